// Round 1
// baseline (1456.191 us; speedup 1.0000x reference)
//
#include <hip/hip_runtime.h>
#include <math.h>

#define BB 64
#define IN_CH 256
#define CH 128
#define OUT_CH 256
#define SP 256        // RES*RES
#define EMBED 64
#define N_EMBED 1024
#define NPH 64
#define FLAT_IN 16384
#define FLAT_Z 4096

__device__ __forceinline__ float silu_f(float x){ return x / (1.0f + expf(-x)); }

// ---- conv_in (1x1) + silu -> h[b][128][256]
__global__ __launch_bounds__(256) void k_conv_in(const float* __restrict__ x,
    const float* __restrict__ w, const float* __restrict__ bias, float* __restrict__ h)
{
  int b = blockIdx.x, dg = blockIdx.y;   // dg<16, 8 d each
  int p = threadIdx.x;
  int d0 = dg*8;
  float acc[8];
  #pragma unroll
  for (int j=0;j<8;j++) acc[j] = bias[d0+j];
  const float* xb = x + (size_t)b*IN_CH*SP + p;
  #pragma unroll 4
  for (int c=0;c<IN_CH;c++){
    float xv = xb[(size_t)c*SP];
    #pragma unroll
    for (int j=0;j<8;j++) acc[j] = fmaf(xv, w[c*CH + d0 + j], acc[j]);
  }
  float* hb = h + (size_t)b*CH*SP + (size_t)d0*SP + p;
  #pragma unroll
  for (int j=0;j<8;j++) hb[(size_t)j*SP] = silu_f(acc[j]);
}

// ---- per-(b,half) LN stats in fp64
__global__ __launch_bounds__(256) void k_stats(const float* __restrict__ h,
    float* __restrict__ mean, float* __restrict__ rstd)
{
  int bx = blockIdx.x;            // b*2+ws
  int b = bx>>1, ws = bx&1;
  const float* base = h + (size_t)b*CH*SP + (size_t)ws*NPH*SP;  // contiguous 16384
  double s1=0.0, s2=0.0;
  for (int i=threadIdx.x; i<FLAT_IN; i+=256){ double v = (double)base[i]; s1+=v; s2+=v*v; }
  __shared__ double l1[256], l2[256];
  l1[threadIdx.x]=s1; l2[threadIdx.x]=s2; __syncthreads();
  for (int s=128; s>0; s>>=1){
    if (threadIdx.x<s){ l1[threadIdx.x]+=l1[threadIdx.x+s]; l2[threadIdx.x]+=l2[threadIdx.x+s]; }
    __syncthreads();
  }
  if (threadIdx.x==0){
    double m = l1[0]/ (double)FLAT_IN;
    double v = l2[0]/ (double)FLAT_IN - m*m;
    mean[bx] = (float)m;
    rstd[bx] = (float)(1.0/sqrt(v+1e-5));
  }
}

// ---- build transposed LN'd activations At[ws][k][m]
__global__ __launch_bounds__(256) void k_build_at(const float* __restrict__ h,
   const float* __restrict__ mean, const float* __restrict__ rstd,
   const float* __restrict__ gp, const float* __restrict__ bp,
   const float* __restrict__ gn, const float* __restrict__ bn,
   float* __restrict__ At)
{
  int kt = blockIdx.x, ws = blockIdx.y;
  int k0 = kt*64;
  const float* g  = ws? gn: gp;
  const float* bb = ws? bn: bp;
  __shared__ float t[64][65];
  int kl = threadIdx.x & 63, mg = threadIdx.x >> 6;
  int k = k0 + kl;
  float gk = g[k], bk = bb[k];
  int ch = k >> 8, pp = k & 255;
  #pragma unroll
  for (int i=0;i<16;i++){
    int m = i*4 + mg;
    float v = h[((size_t)m*CH + ws*NPH + ch)*SP + pp];
    t[kl][m] = fmaf((v - mean[m*2+ws])*rstd[m*2+ws], gk, bk);
  }
  __syncthreads();
  int m2 = threadIdx.x & 63, kg = threadIdx.x >> 6;
  float* dst = At + (size_t)ws*FLAT_IN*64;
  #pragma unroll
  for (int i=0;i<16;i++){
    int kl2 = i*4 + kg;
    dst[(size_t)(k0+kl2)*64 + m2] = t[kl2][m2];
  }
}

// ---- M=64 split-K GEMM: part[ws][kc][m][N] = sum_{k in chunk} At[k][m]*W[k][n]
__global__ __launch_bounds__(256,2) void k_gemm64(
   const float* __restrict__ A,   // [2][K][64]
   const float* __restrict__ W0, const float* __restrict__ W1,
   float* __restrict__ part, int N, int K, int CHUNK, int KC)
{
  int nt = blockIdx.x, kc = blockIdx.y, ws = blockIdx.z;
  const float* W  = ws ? W1 : W0;
  const float* Aw = A + (size_t)ws*K*64;
  int wave = threadIdx.x>>6, lane = threadIdx.x&63;
  int mh = wave&1, nh = wave>>1;
  int n0 = nt*256 + nh*128 + lane;
  int k0 = kc*CHUNK;
  const float* Ak = Aw + (size_t)k0*64 + mh*32;
  const float* Wk = W + (size_t)k0*N + n0;
  float acc0[32], acc1[32];
  #pragma unroll
  for (int i=0;i<32;i++){ acc0[i]=0.f; acc1[i]=0.f; }
  #pragma unroll 4
  for (int k=0;k<CHUNK;k++){
    float w0 = Wk[0], w1 = Wk[64];
    const float4* A4 = (const float4*)Ak;
    #pragma unroll
    for (int i=0;i<8;i++){
      float4 a = A4[i];
      acc0[4*i+0] = fmaf(a.x,w0,acc0[4*i+0]); acc1[4*i+0] = fmaf(a.x,w1,acc1[4*i+0]);
      acc0[4*i+1] = fmaf(a.y,w0,acc0[4*i+1]); acc1[4*i+1] = fmaf(a.y,w1,acc1[4*i+1]);
      acc0[4*i+2] = fmaf(a.z,w0,acc0[4*i+2]); acc1[4*i+2] = fmaf(a.z,w1,acc1[4*i+2]);
      acc0[4*i+3] = fmaf(a.w,w0,acc0[4*i+3]); acc1[4*i+3] = fmaf(a.w,w1,acc1[4*i+3]);
    }
    Ak += 64; Wk += N;
  }
  float* P = part + ((size_t)(ws*KC + kc)*64 + mh*32)*N + n0;
  #pragma unroll
  for (int i=0;i<32;i++){ P[(size_t)i*N] = acc0[i]; P[(size_t)i*N + 64] = acc1[i]; }
}

// ---- z = sum partials + bias; z[ws][m][4096]
__global__ __launch_bounds__(256) void k_zreduce(const float* __restrict__ part,
  const float* __restrict__ bp, const float* __restrict__ bn,
  float* __restrict__ z, int KC)
{
  int idx = blockIdx.x*256 + threadIdx.x;     // < 2*64*4096
  int ws = idx >> 18; int rem = idx & 262143;
  int m = rem >> 12; int n = rem & 4095;
  float s = (ws? bn: bp)[n];
  const float* p = part + ((size_t)ws*KC*64 + m)*4096 + n;
  for (int kc=0;kc<KC;kc++) s += p[(size_t)kc*64*4096];
  z[idx] = s;
}

// ---- codebook squared norms
__global__ __launch_bounds__(256) void k_cc(const float* __restrict__ cb, float* __restrict__ cc){
  int j = blockIdx.x*256 + threadIdx.x;
  if (j >= N_EMBED) return;
  float s=0.f;
  for (int e=0;e<EMBED;e++){ float c = cb[(size_t)j*EMBED+e]; s = fmaf(c,c,s); }
  cc[j]=s;
}

// ---- argmin scan over a 64-code split; score s = cc[j] - 2*z.c[j]
__global__ __launch_bounds__(256) void k_qscan(const float* __restrict__ z,
  const float* __restrict__ cb, const float* __restrict__ cc,
  float* __restrict__ bests, int* __restrict__ bestj)
{
  int r = blockIdx.x*256 + threadIdx.x;   // < 8192
  int cs = blockIdx.y;                    // 16 splits of 64 codes
  int ws = r>>12, rem = r&4095; int b = rem>>6, rr = rem&63;
  const float* zr = z + (size_t)ws*BB*FLAT_Z + (size_t)b*FLAT_Z + rr;
  float zr_[EMBED];
  #pragma unroll
  for (int e=0;e<EMBED;e++) zr_[e] = zr[(size_t)e*64];
  float best = 3.4e38f; int bj = 0;
  int j0 = cs*64;
  for (int jj=0;jj<64;jj++){
    int j = j0 + jj;
    const float* c = cb + (size_t)j*EMBED;
    float s1 = 0.f;
    #pragma unroll
    for (int e=0;e<EMBED;e++) s1 = fmaf(c[e], zr_[e], s1);
    float s = fmaf(-2.f, s1, cc[j]);
    if (s < best){ best = s; bj = j; }   // strict < : first-index semantics
  }
  bests[(size_t)cs*8192 + r] = best;
  bestj[(size_t)cs*8192 + r] = bj;
}

// ---- finalize: combine splits, write zqT[ws][k][m], row sse
__global__ __launch_bounds__(256) void k_qfin(const float* __restrict__ z,
  const float* __restrict__ cb, const float* __restrict__ bests, const int* __restrict__ bestj,
  float* __restrict__ zqT, float* __restrict__ row_sse)
{
  int r = blockIdx.x*256 + threadIdx.x;
  float best = 3.4e38f; int bj = 0;
  for (int cs=0;cs<16;cs++){              // ascending code ranges
    float v = bests[(size_t)cs*8192 + r];
    int j = bestj[(size_t)cs*8192 + r];
    if (v < best){ best=v; bj=j; }
  }
  int ws = r>>12, rem = r&4095; int b = rem>>6, rr = rem&63;
  const float* zr = z + (size_t)ws*BB*FLAT_Z + (size_t)b*FLAT_Z + rr;
  const float* c = cb + (size_t)bj*EMBED;
  float* zq = zqT + (size_t)ws*FLAT_Z*64;
  float sse = 0.f;
  #pragma unroll
  for (int e=0;e<EMBED;e++){
    float cv = c[e];
    float zv = zr[(size_t)e*64];
    float d = cv - zv; sse = fmaf(d,d,sse);
    zq[((size_t)(e*64 + rr))*64 + b] = cv;
  }
  row_sse[r] = sse;
}

// ---- loss reduce (deterministic, fp64)
__global__ __launch_bounds__(256) void k_loss(const float* __restrict__ row_sse, float* __restrict__ out){
  __shared__ double l[256];
  double s=0.0;
  for (int i=threadIdx.x;i<8192;i+=256) s += (double)row_sse[i];
  l[threadIdx.x]=s; __syncthreads();
  for (int st=128;st>0;st>>=1){ if (threadIdx.x<st) l[threadIdx.x]+=l[threadIdx.x+st]; __syncthreads(); }
  if (threadIdx.x==0) out[(size_t)BB*OUT_CH*SP] = (float)(l[0]*1.25/262144.0);
}

// ---- hout reduce + bias -> h_[m][128][256] (reuses h buffer)
__global__ __launch_bounds__(256) void k_hreduce(const float* __restrict__ part,
  const float* __restrict__ bp, const float* __restrict__ bn,
  float* __restrict__ hbuf, int KC)
{
  int idx = blockIdx.x*256 + threadIdx.x;  // < 2*64*16384
  int ws = idx >> 20; int rem = idx & 1048575;
  int m = rem >> 14; int n = rem & 16383;
  float s = (ws? bn: bp)[n];
  const float* p = part + ((size_t)ws*KC*64 + m)*16384 + n;
  for (int kc=0;kc<KC;kc++) s += p[(size_t)kc*64*16384];
  hbuf[((size_t)m*CH + ws*NPH + (n>>8))*SP + (n&255)] = s;
}

// ---- conv_out (silu on input) -> d_out
__global__ __launch_bounds__(256) void k_conv_out(const float* __restrict__ hbuf,
  const float* __restrict__ w2, const float* __restrict__ b2, float* __restrict__ out)
{
  int b = blockIdx.x, dg = blockIdx.y; // 32 groups of 8
  int p = threadIdx.x;
  int d0 = dg*8;
  float acc[8];
  #pragma unroll
  for (int j=0;j<8;j++) acc[j]=b2[d0+j];
  const float* hb = hbuf + (size_t)b*CH*SP + p;
  #pragma unroll 2
  for (int c=0;c<CH;c++){
    float hv = silu_f(hb[(size_t)c*SP]);
    #pragma unroll
    for (int j=0;j<8;j++) acc[j] = fmaf(hv, w2[c*OUT_CH + d0 + j], acc[j]);
  }
  float* ob = out + (size_t)b*OUT_CH*SP + (size_t)d0*SP + p;
  #pragma unroll
  for (int j=0;j<8;j++) ob[(size_t)j*SP] = acc[j];
}

extern "C" void kernel_launch(void* const* d_in, const int* in_sizes, int n_in,
                              void* d_out, int out_size, void* d_ws, size_t ws_size,
                              hipStream_t stream)
{
  const float* x   = (const float*)d_in[0];
  const float* w1  = (const float*)d_in[1];
  const float* b1  = (const float*)d_in[2];
  const float* gp  = (const float*)d_in[3];
  const float* bp  = (const float*)d_in[4];
  const float* Wip = (const float*)d_in[5];
  const float* bip = (const float*)d_in[6];
  const float* gn  = (const float*)d_in[7];
  const float* bnl = (const float*)d_in[8];
  const float* Win = (const float*)d_in[9];
  const float* bin = (const float*)d_in[10];
  const float* cb  = (const float*)d_in[11];
  const float* Wop = (const float*)d_in[12];
  const float* bop = (const float*)d_in[13];
  const float* Won = (const float*)d_in[14];
  const float* bon = (const float*)d_in[15];
  const float* w2  = (const float*)d_in[16];
  const float* b2  = (const float*)d_in[17];
  float* out = (float*)d_out;
  float* ws  = (float*)d_ws;

  float* h    = ws;                   // 2,097,152
  float* At   = ws + 2097152;         // 2,097,152
  float* z    = ws + 4194304;         // 524,288
  float* zqT  = ws + 4718592;         // 524,288
  float* mean = ws + 5242880;         // 128
  float* rstd = ws + 5243008;         // 128
  float* cc   = ws + 5243136;         // 1024
  float* sse  = ws + 5244160;         // 8192
  float* bests= ws + 5252352;         // 131072
  int*   bestj= (int*)(ws + 5383424); // 131072
  float* part = ws + 5514496;

  size_t wsf = ws_size/4;
  int KCe=16, KCd=4;
  if (wsf < (size_t)5514496 + 8388608) { KCe=8; KCd=2; }
  if (wsf < (size_t)5514496 + 4194304) { KCe=4; KCd=1; }

  k_conv_in<<<dim3(64,16),256,0,stream>>>(x,w1,b1,h);
  k_stats<<<128,256,0,stream>>>(h,mean,rstd);
  k_build_at<<<dim3(256,2),256,0,stream>>>(h,mean,rstd,gp,bp,gn,bnl,At);
  k_gemm64<<<dim3(16,KCe,2),256,0,stream>>>(At,Wip,Win,part,4096,16384,16384/KCe,KCe);
  k_zreduce<<<2048,256,0,stream>>>(part,bip,bin,z,KCe);
  k_cc<<<4,256,0,stream>>>(cb,cc);
  k_qscan<<<dim3(32,16),256,0,stream>>>(z,cb,cc,bests,bestj);
  k_qfin<<<32,256,0,stream>>>(z,cb,bests,bestj,zqT,sse);
  k_gemm64<<<dim3(64,KCd,2),256,0,stream>>>(zqT,Wop,Won,part,16384,4096,4096/KCd,KCd);
  k_hreduce<<<8192,256,0,stream>>>(part,bop,bon,h,KCd);
  k_conv_out<<<dim3(64,32),256,0,stream>>>(h,w2,b2,out);
  k_loss<<<1,256,0,stream>>>(sse,out);
}

// Round 2
// 722.393 us; speedup vs baseline: 2.0158x; 2.0158x over previous
//
#include <hip/hip_runtime.h>
#include <math.h>

#define BB 64
#define IN_CH 256
#define CH 128
#define OUT_CH 256
#define SP 256        // RES*RES
#define EMBED 64
#define N_EMBED 1024
#define NPH 64
#define FLAT_IN 16384
#define FLAT_Z 4096

__device__ __forceinline__ float silu_f(float x){ return x / (1.0f + expf(-x)); }

// ---- conv_in (1x1) + silu -> h[b][128][256]; dg<4, 32 d each
__global__ __launch_bounds__(256) void k_conv_in(const float* __restrict__ x,
    const float* __restrict__ w, const float* __restrict__ bias, float* __restrict__ h)
{
  int b = blockIdx.x, dg = blockIdx.y;
  int p = threadIdx.x;
  int d0 = dg*32;
  float acc[32];
  #pragma unroll
  for (int j=0;j<32;j++) acc[j] = bias[d0+j];
  const float* xb = x + (size_t)b*IN_CH*SP + p;
  for (int c=0;c<IN_CH;c++){
    float xv = xb[(size_t)c*SP];
    #pragma unroll
    for (int j=0;j<32;j++) acc[j] = fmaf(xv, w[c*CH + d0 + j], acc[j]);
  }
  float* hb = h + (size_t)b*CH*SP + (size_t)d0*SP + p;
  #pragma unroll
  for (int j=0;j<32;j++) hb[(size_t)j*SP] = silu_f(acc[j]);
}

// ---- per-(b,half) LN stats in fp64
__global__ __launch_bounds__(256) void k_stats(const float* __restrict__ h,
    float* __restrict__ mean, float* __restrict__ rstd)
{
  int bx = blockIdx.x;            // b*2+ws
  int b = bx>>1, ws = bx&1;
  const float* base = h + (size_t)b*CH*SP + (size_t)ws*NPH*SP;  // contiguous 16384
  double s1=0.0, s2=0.0;
  for (int i=threadIdx.x; i<FLAT_IN; i+=256){ double v = (double)base[i]; s1+=v; s2+=v*v; }
  __shared__ double l1[256], l2[256];
  l1[threadIdx.x]=s1; l2[threadIdx.x]=s2; __syncthreads();
  for (int s=128; s>0; s>>=1){
    if (threadIdx.x<s){ l1[threadIdx.x]+=l1[threadIdx.x+s]; l2[threadIdx.x]+=l2[threadIdx.x+s]; }
    __syncthreads();
  }
  if (threadIdx.x==0){
    double m = l1[0]/ (double)FLAT_IN;
    double v = l2[0]/ (double)FLAT_IN - m*m;
    mean[bx] = (float)m;
    rstd[bx] = (float)(1.0/sqrt(v+1e-5));
  }
}

// ---- build transposed LN'd activations At[ws][k][m]
__global__ __launch_bounds__(256) void k_build_at(const float* __restrict__ h,
   const float* __restrict__ mean, const float* __restrict__ rstd,
   const float* __restrict__ gp, const float* __restrict__ bp,
   const float* __restrict__ gn, const float* __restrict__ bn,
   float* __restrict__ At)
{
  int kt = blockIdx.x, ws = blockIdx.y;
  int k0 = kt*64;
  const float* g  = ws? gn: gp;
  const float* bb = ws? bn: bp;
  __shared__ float t[64][65];
  int kl = threadIdx.x & 63, mg = threadIdx.x >> 6;
  int k = k0 + kl;
  float gk = g[k], bk = bb[k];
  int ch = k >> 8, pp = k & 255;
  #pragma unroll
  for (int i=0;i<16;i++){
    int m = i*4 + mg;
    float v = h[((size_t)m*CH + ws*NPH + ch)*SP + pp];
    t[kl][m] = fmaf((v - mean[m*2+ws])*rstd[m*2+ws], gk, bk);
  }
  __syncthreads();
  int m2 = threadIdx.x & 63, kg = threadIdx.x >> 6;
  float* dst = At + (size_t)ws*FLAT_IN*64;
  #pragma unroll
  for (int i=0;i<16;i++){
    int kl2 = i*4 + kg;
    dst[(size_t)(k0+kl2)*64 + m2] = t[kl2][m2];
  }
}

// ---- LDS-tiled M=64 split-K GEMM: tile 64m x 128n, KB=32, reg-prefetch
// part[ws][kc][m][N] = sum_{k in chunk} At[k][m]*W[k][n]
#define FMA_ROW(J, AV) \
  acc[J].x = fmaf(AV, w.x, acc[J].x); \
  acc[J].y = fmaf(AV, w.y, acc[J].y); \
  acc[J].z = fmaf(AV, w.z, acc[J].z); \
  acc[J].w = fmaf(AV, w.w, acc[J].w);

__global__ __launch_bounds__(256) void k_gemm_lds(
   const float* __restrict__ A,   // [2][K][64]
   const float* __restrict__ W0, const float* __restrict__ W1,
   float* __restrict__ part, int N, int K, int CHUNK, int KC)
{
  __shared__ float a_lds[2048];   // 32k x 64m
  __shared__ float w_lds[4096];   // 32k x 128n
  int nt = blockIdx.x, kc = blockIdx.y, wsel = blockIdx.z;
  const float* W  = wsel ? W1 : W0;
  const float* Aw = A + (size_t)wsel*K*64;
  int t = threadIdx.x;
  int ng4 = (t & 31) * 4;      // n within tile (x4)
  int mg8 = (t >> 5) * 8;      // m group (8 m per thread)
  int k0 = kc*CHUNK;
  const float* Ag = Aw + (size_t)k0*64;
  const float* Wg = W  + (size_t)k0*N + (size_t)nt*128;

  float4 acc[8];
  #pragma unroll
  for (int j=0;j<8;j++) acc[j] = make_float4(0.f,0.f,0.f,0.f);

  int fa0 = t*4, fa1 = 1024 + t*4;
  int fw0, fw1, fw2, fw3;
  { int f0 = t*4;        fw0 = (f0>>7)*N + (f0&127);
    int f1 = 1024 + t*4; fw1 = (f1>>7)*N + (f1&127);
    int f2 = 2048 + t*4; fw2 = (f2>>7)*N + (f2&127);
    int f3 = 3072 + t*4; fw3 = (f3>>7)*N + (f3&127); }

  int NT = CHUNK/32;
  float4 ar0 = *(const float4*)&Ag[fa0];
  float4 ar1 = *(const float4*)&Ag[fa1];
  float4 wr0 = *(const float4*)&Wg[fw0];
  float4 wr1 = *(const float4*)&Wg[fw1];
  float4 wr2 = *(const float4*)&Wg[fw2];
  float4 wr3 = *(const float4*)&Wg[fw3];

  for (int kb=0; kb<NT; kb++){
    __syncthreads();   // all waves done reading LDS from previous tile
    *(float4*)&a_lds[fa0] = ar0;
    *(float4*)&a_lds[fa1] = ar1;
    *(float4*)&w_lds[t*4       ] = wr0;
    *(float4*)&w_lds[1024 + t*4] = wr1;
    *(float4*)&w_lds[2048 + t*4] = wr2;
    *(float4*)&w_lds[3072 + t*4] = wr3;
    if (kb+1 < NT){
      const float* Agn = Ag + (size_t)(kb+1)*2048;
      const float* Wgn = Wg + (size_t)(kb+1)*32*N;
      ar0 = *(const float4*)&Agn[fa0];
      ar1 = *(const float4*)&Agn[fa1];
      wr0 = *(const float4*)&Wgn[fw0];
      wr1 = *(const float4*)&Wgn[fw1];
      wr2 = *(const float4*)&Wgn[fw2];
      wr3 = *(const float4*)&Wgn[fw3];
    }
    __syncthreads();   // LDS tile ready
    #pragma unroll 4
    for (int k=0;k<32;k++){
      float4 w  = *(const float4*)&w_lds[k*128 + ng4];
      float4 a0 = *(const float4*)&a_lds[k*64 + mg8];
      float4 a1 = *(const float4*)&a_lds[k*64 + mg8 + 4];
      FMA_ROW(0, a0.x) FMA_ROW(1, a0.y) FMA_ROW(2, a0.z) FMA_ROW(3, a0.w)
      FMA_ROW(4, a1.x) FMA_ROW(5, a1.y) FMA_ROW(6, a1.z) FMA_ROW(7, a1.w)
    }
  }
  float* P = part + ((size_t)(wsel*KC + kc)*64 + mg8)*N + (size_t)nt*128 + ng4;
  #pragma unroll
  for (int j=0;j<8;j++) *(float4*)&P[(size_t)j*N] = acc[j];
}

// ---- z = sum partials + bias; z[ws][m][4096]
__global__ __launch_bounds__(256) void k_zreduce(const float* __restrict__ part,
  const float* __restrict__ bp, const float* __restrict__ bn,
  float* __restrict__ z, int KC)
{
  int idx = blockIdx.x*256 + threadIdx.x;     // < 2*64*4096
  int ws = idx >> 18; int rem = idx & 262143;
  int m = rem >> 12; int n = rem & 4095;
  float s = (ws? bn: bp)[n];
  const float* p = part + ((size_t)ws*KC*64 + m)*4096 + n;
  for (int kc=0;kc<KC;kc++) s += p[(size_t)kc*64*4096];
  z[idx] = s;
}

// ---- codebook squared norms
__global__ __launch_bounds__(256) void k_cc(const float* __restrict__ cb, float* __restrict__ cc){
  int j = blockIdx.x*256 + threadIdx.x;
  if (j >= N_EMBED) return;
  float s=0.f;
  for (int e=0;e<EMBED;e++){ float c = cb[(size_t)j*EMBED+e]; s = fmaf(c,c,s); }
  cc[j]=s;
}

// ---- argmin scan over a 64-code split; score s = cc[j] - 2*z.c[j]
__global__ __launch_bounds__(256) void k_qscan(const float* __restrict__ z,
  const float* __restrict__ cb, const float* __restrict__ cc,
  float* __restrict__ bests, int* __restrict__ bestj)
{
  int r = blockIdx.x*256 + threadIdx.x;   // < 8192
  int cs = blockIdx.y;                    // 16 splits of 64 codes
  int ws = r>>12, rem = r&4095; int b = rem>>6, rr = rem&63;
  const float* zr = z + (size_t)ws*BB*FLAT_Z + (size_t)b*FLAT_Z + rr;
  float zr_[EMBED];
  #pragma unroll
  for (int e=0;e<EMBED;e++) zr_[e] = zr[(size_t)e*64];
  float best = 3.4e38f; int bj = 0;
  int j0 = cs*64;
  for (int jj=0;jj<64;jj++){
    int j = j0 + jj;
    const float* c = cb + (size_t)j*EMBED;
    float s1 = 0.f;
    #pragma unroll
    for (int e=0;e<EMBED;e++) s1 = fmaf(c[e], zr_[e], s1);
    float s = fmaf(-2.f, s1, cc[j]);
    if (s < best){ best = s; bj = j; }   // strict < : first-index semantics
  }
  bests[(size_t)cs*8192 + r] = best;
  bestj[(size_t)cs*8192 + r] = bj;
}

// ---- finalize: combine splits, write zqT[ws][k][m], row sse
__global__ __launch_bounds__(256) void k_qfin(const float* __restrict__ z,
  const float* __restrict__ cb, const float* __restrict__ bests, const int* __restrict__ bestj,
  float* __restrict__ zqT, float* __restrict__ row_sse)
{
  int r = blockIdx.x*256 + threadIdx.x;
  float best = 3.4e38f; int bj = 0;
  for (int cs=0;cs<16;cs++){              // ascending code ranges
    float v = bests[(size_t)cs*8192 + r];
    int j = bestj[(size_t)cs*8192 + r];
    if (v < best){ best=v; bj=j; }
  }
  int ws = r>>12, rem = r&4095; int b = rem>>6, rr = rem&63;
  const float* zr = z + (size_t)ws*BB*FLAT_Z + (size_t)b*FLAT_Z + rr;
  const float* c = cb + (size_t)bj*EMBED;
  float* zq = zqT + (size_t)ws*FLAT_Z*64;
  float sse = 0.f;
  #pragma unroll
  for (int e=0;e<EMBED;e++){
    float cv = c[e];
    float zv = zr[(size_t)e*64];
    float d = cv - zv; sse = fmaf(d,d,sse);
    zq[((size_t)(e*64 + rr))*64 + b] = cv;
  }
  row_sse[r] = sse;
}

// ---- loss reduce (deterministic, fp64)
__global__ __launch_bounds__(256) void k_loss(const float* __restrict__ row_sse, float* __restrict__ out){
  __shared__ double l[256];
  double s=0.0;
  for (int i=threadIdx.x;i<8192;i+=256) s += (double)row_sse[i];
  l[threadIdx.x]=s; __syncthreads();
  for (int st=128;st>0;st>>=1){ if (threadIdx.x<st) l[threadIdx.x]+=l[threadIdx.x+st]; __syncthreads(); }
  if (threadIdx.x==0) out[(size_t)BB*OUT_CH*SP] = (float)(l[0]*1.25/262144.0);
}

// ---- hout reduce + bias -> h_[m][128][256] (reuses h buffer)
__global__ __launch_bounds__(256) void k_hreduce(const float* __restrict__ part,
  const float* __restrict__ bp, const float* __restrict__ bn,
  float* __restrict__ hbuf, int KC)
{
  int idx = blockIdx.x*256 + threadIdx.x;  // < 2*64*16384
  int ws = idx >> 20; int rem = idx & 1048575;
  int m = rem >> 14; int n = rem & 16383;
  float s = (ws? bn: bp)[n];
  const float* p = part + ((size_t)ws*KC*64 + m)*16384 + n;
  for (int kc=0;kc<KC;kc++) s += p[(size_t)kc*64*16384];
  hbuf[((size_t)m*CH + ws*NPH + (n>>8))*SP + (n&255)] = s;
}

// ---- conv_out (silu on input) -> d_out; dg<4, 64 d each
__global__ __launch_bounds__(256) void k_conv_out(const float* __restrict__ hbuf,
  const float* __restrict__ w2, const float* __restrict__ b2, float* __restrict__ out)
{
  int b = blockIdx.x, dg = blockIdx.y;
  int p = threadIdx.x;
  int d0 = dg*64;
  float acc[64];
  #pragma unroll
  for (int j=0;j<64;j++) acc[j]=b2[d0+j];
  const float* hb = hbuf + (size_t)b*CH*SP + p;
  for (int c=0;c<CH;c++){
    float hv = silu_f(hb[(size_t)c*SP]);
    #pragma unroll
    for (int j=0;j<64;j++) acc[j] = fmaf(hv, w2[c*OUT_CH + d0 + j], acc[j]);
  }
  float* ob = out + (size_t)b*OUT_CH*SP + (size_t)d0*SP + p;
  #pragma unroll
  for (int j=0;j<64;j++) ob[(size_t)j*SP] = acc[j];
}

extern "C" void kernel_launch(void* const* d_in, const int* in_sizes, int n_in,
                              void* d_out, int out_size, void* d_ws, size_t ws_size,
                              hipStream_t stream)
{
  const float* x   = (const float*)d_in[0];
  const float* w1  = (const float*)d_in[1];
  const float* b1  = (const float*)d_in[2];
  const float* gp  = (const float*)d_in[3];
  const float* bp  = (const float*)d_in[4];
  const float* Wip = (const float*)d_in[5];
  const float* bip = (const float*)d_in[6];
  const float* gn  = (const float*)d_in[7];
  const float* bnl = (const float*)d_in[8];
  const float* Win = (const float*)d_in[9];
  const float* bin = (const float*)d_in[10];
  const float* cb  = (const float*)d_in[11];
  const float* Wop = (const float*)d_in[12];
  const float* bop = (const float*)d_in[13];
  const float* Won = (const float*)d_in[14];
  const float* bon = (const float*)d_in[15];
  const float* w2  = (const float*)d_in[16];
  const float* b2  = (const float*)d_in[17];
  float* out = (float*)d_out;
  float* ws  = (float*)d_ws;

  float* h    = ws;                   // 2,097,152
  float* At   = ws + 2097152;         // 2,097,152
  float* z    = ws + 4194304;         // 524,288
  float* zqT  = ws + 4718592;         // 524,288
  float* mean = ws + 5242880;         // 128
  float* rstd = ws + 5243008;         // 128
  float* cc   = ws + 5243136;         // 1024
  float* sse  = ws + 5244160;         // 8192
  float* bests= ws + 5252352;         // 131072
  int*   bestj= (int*)(ws + 5383424); // 131072
  float* part = ws + 5514496;

  size_t wsf = ws_size/4;
  int KCe=16, KCd=4;
  if (wsf < (size_t)5514496 + 8388608) { KCe=8; KCd=2; }
  if (wsf < (size_t)5514496 + 4194304) { KCe=4; KCd=1; }

  k_conv_in<<<dim3(64,4),256,0,stream>>>(x,w1,b1,h);
  k_stats<<<128,256,0,stream>>>(h,mean,rstd);
  k_build_at<<<dim3(256,2),256,0,stream>>>(h,mean,rstd,gp,bp,gn,bnl,At);
  k_gemm_lds<<<dim3(32,KCe,2),256,0,stream>>>(At,Wip,Win,part,4096,16384,16384/KCe,KCe);
  k_zreduce<<<2048,256,0,stream>>>(part,bip,bin,z,KCe);
  k_cc<<<4,256,0,stream>>>(cb,cc);
  k_qscan<<<dim3(32,16),256,0,stream>>>(z,cb,cc,bests,bestj);
  k_qfin<<<32,256,0,stream>>>(z,cb,bests,bestj,zqT,sse);
  k_gemm_lds<<<dim3(128,KCd,2),256,0,stream>>>(zqT,Wop,Won,part,16384,4096,4096/KCd,KCd);
  k_hreduce<<<8192,256,0,stream>>>(part,bop,bon,h,KCd);
  k_conv_out<<<dim3(64,4),256,0,stream>>>(h,w2,b2,out);
  k_loss<<<1,256,0,stream>>>(sse,out);
}

// Round 3
// 608.673 us; speedup vs baseline: 2.3924x; 1.1868x over previous
//
#include <hip/hip_runtime.h>
#include <hip/hip_bf16.h>
#include <math.h>

#define BB 64
#define IN_CH 256
#define CH 128
#define OUT_CH 256
#define SP 256        // RES*RES
#define EMBED 64
#define N_EMBED 1024
#define NPH 64
#define FLAT_IN 16384
#define FLAT_Z 4096

typedef short bf16x8 __attribute__((ext_vector_type(8)));
typedef float f32x4 __attribute__((ext_vector_type(4)));

__device__ __forceinline__ float silu_f(float x){ return x / (1.0f + expf(-x)); }

// ---- conv_in (1x1) + silu -> h[b][128][256]; dg<2, 64 d each
__global__ __launch_bounds__(256) void k_conv_in(const float* __restrict__ x,
    const float* __restrict__ w, const float* __restrict__ bias, float* __restrict__ h)
{
  int b = blockIdx.x, dg = blockIdx.y;
  int p = threadIdx.x;
  int d0 = dg*64;
  float acc[64];
  #pragma unroll
  for (int j=0;j<64;j++) acc[j] = bias[d0+j];
  const float* xb = x + (size_t)b*IN_CH*SP + p;
  for (int c=0;c<IN_CH;c++){
    float xv = xb[(size_t)c*SP];
    #pragma unroll
    for (int j=0;j<64;j++) acc[j] = fmaf(xv, w[c*CH + d0 + j], acc[j]);
  }
  float* hb = h + (size_t)b*CH*SP + (size_t)d0*SP + p;
  #pragma unroll
  for (int j=0;j<64;j++) hb[(size_t)j*SP] = silu_f(acc[j]);
}

// ---- fused: per-(b,half) LN stats (fp64) + LN apply + bf16 hi/lo split
// writes Ahi/Alo [2][64][16384] bf16, m-major (k contiguous)
__global__ __launch_bounds__(256) void k_stats_build(const float* __restrict__ h,
    const float* __restrict__ gp, const float* __restrict__ bp,
    const float* __restrict__ gn, const float* __restrict__ bnl,
    __hip_bfloat16* __restrict__ Ahi, __hip_bfloat16* __restrict__ Alo)
{
  int bx = blockIdx.x;            // b*2+ws
  int b = bx>>1, ws = bx&1;
  int t = threadIdx.x;
  const float* base = h + (size_t)b*CH*SP + (size_t)ws*NPH*SP;  // contiguous 16384
  double s1=0.0, s2=0.0;
  for (int i=t; i<FLAT_IN; i+=256){ double v = (double)base[i]; s1+=v; s2+=v*v; }
  __shared__ double l1[256], l2[256];
  l1[t]=s1; l2[t]=s2; __syncthreads();
  for (int s=128; s>0; s>>=1){
    if (t<s){ l1[t]+=l1[t+s]; l2[t]+=l2[t+s]; }
    __syncthreads();
  }
  double m = l1[0]/(double)FLAT_IN;
  double v = l2[0]/(double)FLAT_IN - m*m;
  float mf = (float)m;
  float rs = (float)(1.0/sqrt(v+1e-5));
  const float* g  = ws? gn : gp;
  const float* bb = ws? bnl: bp;
  __hip_bfloat16* oh = Ahi + ((size_t)ws*64 + b)*FLAT_IN;
  __hip_bfloat16* ol = Alo + ((size_t)ws*64 + b)*FLAT_IN;
  for (int i=t; i<FLAT_IN; i+=256){
    float val = fmaf((base[i]-mf)*rs, g[i], bb[i]);
    __hip_bfloat16 hb = __float2bfloat16(val);
    oh[i] = hb;
    ol[i] = __float2bfloat16(val - __bfloat162float(hb));
  }
}

// ---- MFMA split-K GEMM, M=64. A: bf16 hi/lo [2][64][K]. W: fp32 [K][N] split hi/lo in-reg.
// PASSES==3: hi*hi + hi*lo + lo*hi (fp32-emulation, encoder). PASSES==1: bf16 (decoder).
// part[(wsel*KC+kc)*64 + m][N]
template<int N, int K, int PASSES>
__global__ __launch_bounds__(256) void k_gemm_mfma(
    const __hip_bfloat16* __restrict__ Ahi, const __hip_bfloat16* __restrict__ Alo,
    const float* __restrict__ W0, const float* __restrict__ W1,
    float* __restrict__ part, int CHUNK, int KC)
{
  int nt = blockIdx.x, kc = blockIdx.y, wsel = blockIdx.z;
  const float* W = wsel ? W1 : W0;
  int t = threadIdx.x;
  int wave = t >> 6, lane = t & 63;
  int rl = lane & 15;              // row/col-in-frag
  int kg = (lane >> 4) * 8;        // k-group base within 32
  int nbase = nt*128 + wave*32;    // wave's 32-col slice
  int k0 = kc*CHUNK;

  const __hip_bfloat16* Ah = Ahi + (size_t)wsel*64*K;
  const __hip_bfloat16* Al = Alo + (size_t)wsel*64*K;
  const float* wp = W + ((size_t)(k0 + kg))*N + nbase + rl;

  f32x4 acc[4][2];
  #pragma unroll
  for (int mf=0; mf<4; ++mf)
    #pragma unroll
    for (int f=0; f<2; ++f)
      acc[mf][f] = (f32x4){0.f,0.f,0.f,0.f};

  float b0[2][8], b1[2][8];
  bf16x8 a0h[4], a0l[4], a1h[4], a1l[4];

  auto loadB = [&](float (&buf)[2][8], int ksv){
    const float* _wp = wp + (size_t)ksv*32*N;
    #pragma unroll
    for (int f=0; f<2; ++f)
      #pragma unroll
      for (int j=0; j<8; ++j)
        buf[f][j] = _wp[(size_t)j*N + f*16];
  };
  auto loadA = [&](bf16x8 (&ah)[4], bf16x8 (&al)[4], int ksv){
    size_t ko = (size_t)k0 + (size_t)ksv*32 + kg;
    #pragma unroll
    for (int mf=0; mf<4; ++mf){
      ah[mf] = *(const bf16x8*)(Ah + ((size_t)(mf*16+rl))*K + ko);
      if (PASSES==3) al[mf] = *(const bf16x8*)(Al + ((size_t)(mf*16+rl))*K + ko);
    }
  };
  auto compute = [&](float (&buf)[2][8], bf16x8 (&ah)[4], bf16x8 (&al)[4]){
    bf16x8 bh[2], bl[2];
    #pragma unroll
    for (int f=0; f<2; ++f)
      #pragma unroll
      for (int j=0; j<8; ++j){
        float w = buf[f][j];
        __hip_bfloat16 hb = __float2bfloat16(w);
        bh[f][j] = __builtin_bit_cast(short, hb);
        if (PASSES==3){
          float r = w - __bfloat162float(hb);
          __hip_bfloat16 lb = __float2bfloat16(r);
          bl[f][j] = __builtin_bit_cast(short, lb);
        }
      }
    #pragma unroll
    for (int mf=0; mf<4; ++mf)
      #pragma unroll
      for (int f=0; f<2; ++f)
        acc[mf][f] = __builtin_amdgcn_mfma_f32_16x16x32_bf16(ah[mf], bh[f], acc[mf][f], 0,0,0);
    if (PASSES==3){
      #pragma unroll
      for (int mf=0; mf<4; ++mf)
        #pragma unroll
        for (int f=0; f<2; ++f)
          acc[mf][f] = __builtin_amdgcn_mfma_f32_16x16x32_bf16(ah[mf], bl[f], acc[mf][f], 0,0,0);
      #pragma unroll
      for (int mf=0; mf<4; ++mf)
        #pragma unroll
        for (int f=0; f<2; ++f)
          acc[mf][f] = __builtin_amdgcn_mfma_f32_16x16x32_bf16(al[mf], bh[f], acc[mf][f], 0,0,0);
    }
  };

  int NT = CHUNK/32;   // even for all KC configs
  loadB(b0, 0); loadA(a0h, a0l, 0);
  for (int ks2=0; ks2<NT/2; ++ks2){
    loadB(b1, 2*ks2+1); loadA(a1h, a1l, 2*ks2+1);
    compute(b0, a0h, a0l);
    if (ks2+1 < NT/2){ loadB(b0, 2*ks2+2); loadA(a0h, a0l, 2*ks2+2); }
    compute(b1, a1h, a1l);
  }

  float* P = part + ((size_t)((wsel*KC + kc)*64))*N + nbase + rl;
  int rbase = ((lane>>4)&3)*4;
  #pragma unroll
  for (int mf=0; mf<4; ++mf)
    #pragma unroll
    for (int f=0; f<2; ++f)
      #pragma unroll
      for (int r=0; r<4; ++r)
        P[((size_t)(mf*16 + rbase + r))*N + f*16] = acc[mf][f][r];
}

// ---- z = sum partials + bias; z[ws][m][4096]
__global__ __launch_bounds__(256) void k_zreduce(const float* __restrict__ part,
  const float* __restrict__ bp, const float* __restrict__ bn,
  float* __restrict__ z, int KC)
{
  int idx = blockIdx.x*256 + threadIdx.x;     // < 2*64*4096
  int ws = idx >> 18; int rem = idx & 262143;
  int m = rem >> 12; int n = rem & 4095;
  float s = (ws? bn: bp)[n];
  const float* p = part + ((size_t)ws*KC*64 + m)*4096 + n;
  for (int kc=0;kc<KC;kc++) s += p[(size_t)kc*64*4096];
  z[idx] = s;
}

// ---- codebook squared norms
__global__ __launch_bounds__(256) void k_cc(const float* __restrict__ cb, float* __restrict__ cc){
  int j = blockIdx.x*256 + threadIdx.x;
  if (j >= N_EMBED) return;
  float s=0.f;
  for (int e=0;e<EMBED;e++){ float c = cb[(size_t)j*EMBED+e]; s = fmaf(c,c,s); }
  cc[j]=s;
}

// ---- argmin scan over a 64-code split; score s = cc[j] - 2*z.c[j]
__global__ __launch_bounds__(256) void k_qscan(const float* __restrict__ z,
  const float* __restrict__ cb, const float* __restrict__ cc,
  float* __restrict__ bests, int* __restrict__ bestj)
{
  int r = blockIdx.x*256 + threadIdx.x;   // < 8192
  int cs = blockIdx.y;                    // 16 splits of 64 codes
  int ws = r>>12, rem = r&4095; int b = rem>>6, rr = rem&63;
  const float* zr = z + (size_t)ws*BB*FLAT_Z + (size_t)b*FLAT_Z + rr;
  float zr_[EMBED];
  #pragma unroll
  for (int e=0;e<EMBED;e++) zr_[e] = zr[(size_t)e*64];
  float best = 3.4e38f; int bj = 0;
  int j0 = cs*64;
  for (int jj=0;jj<64;jj++){
    int j = j0 + jj;
    const float* c = cb + (size_t)j*EMBED;
    float s1 = 0.f;
    #pragma unroll
    for (int e=0;e<EMBED;e++) s1 = fmaf(c[e], zr_[e], s1);
    float s = fmaf(-2.f, s1, cc[j]);
    if (s < best){ best = s; bj = j; }   // strict < : first-index semantics
  }
  bests[(size_t)cs*8192 + r] = best;
  bestj[(size_t)cs*8192 + r] = bj;
}

// ---- finalize: combine splits, write zqA bf16 [ws][b][4096], row sse
__global__ __launch_bounds__(256) void k_qfin(const float* __restrict__ z,
  const float* __restrict__ cb, const float* __restrict__ bests, const int* __restrict__ bestj,
  __hip_bfloat16* __restrict__ zqA, float* __restrict__ row_sse)
{
  int r = blockIdx.x*256 + threadIdx.x;
  float best = 3.4e38f; int bj = 0;
  for (int cs=0;cs<16;cs++){              // ascending code ranges
    float v = bests[(size_t)cs*8192 + r];
    int j = bestj[(size_t)cs*8192 + r];
    if (v < best){ best=v; bj=j; }
  }
  int ws = r>>12, rem = r&4095; int b = rem>>6, rr = rem&63;
  const float* zr = z + (size_t)ws*BB*FLAT_Z + (size_t)b*FLAT_Z + rr;
  const float* c = cb + (size_t)bj*EMBED;
  __hip_bfloat16* zq = zqA + ((size_t)ws*64 + b)*FLAT_Z;
  float sse = 0.f;
  #pragma unroll
  for (int e=0;e<EMBED;e++){
    float cv = c[e];
    float zv = zr[(size_t)e*64];
    float d = cv - zv; sse = fmaf(d,d,sse);
    zq[(size_t)e*64 + rr] = __float2bfloat16(cv);
  }
  row_sse[r] = sse;
}

// ---- loss reduce (deterministic, fp64)
__global__ __launch_bounds__(256) void k_loss(const float* __restrict__ row_sse, float* __restrict__ out){
  __shared__ double l[256];
  double s=0.0;
  for (int i=threadIdx.x;i<8192;i+=256) s += (double)row_sse[i];
  l[threadIdx.x]=s; __syncthreads();
  for (int st=128;st>0;st>>=1){ if (threadIdx.x<st) l[threadIdx.x]+=l[threadIdx.x+st]; __syncthreads(); }
  if (threadIdx.x==0) out[(size_t)BB*OUT_CH*SP] = (float)(l[0]*1.25/262144.0);
}

// ---- hout reduce + bias -> h_[m][128][256] (reuses h buffer)
__global__ __launch_bounds__(256) void k_hreduce(const float* __restrict__ part,
  const float* __restrict__ bp, const float* __restrict__ bn,
  float* __restrict__ hbuf, int KC)
{
  int idx = blockIdx.x*256 + threadIdx.x;  // < 2*64*16384
  int ws = idx >> 20; int rem = idx & 1048575;
  int m = rem >> 14; int n = rem & 16383;
  float s = (ws? bn: bp)[n];
  const float* p = part + ((size_t)ws*KC*64 + m)*16384 + n;
  for (int kc=0;kc<KC;kc++) s += p[(size_t)kc*64*16384];
  hbuf[((size_t)m*CH + ws*NPH + (n>>8))*SP + (n&255)] = s;
}

// ---- conv_out (silu on input) -> d_out; dg<4, 64 d each
__global__ __launch_bounds__(256) void k_conv_out(const float* __restrict__ hbuf,
  const float* __restrict__ w2, const float* __restrict__ b2, float* __restrict__ out)
{
  int b = blockIdx.x, dg = blockIdx.y;
  int p = threadIdx.x;
  int d0 = dg*64;
  float acc[64];
  #pragma unroll
  for (int j=0;j<64;j++) acc[j]=b2[d0+j];
  const float* hb = hbuf + (size_t)b*CH*SP + p;
  for (int c=0;c<CH;c++){
    float hv = silu_f(hb[(size_t)c*SP]);
    #pragma unroll
    for (int j=0;j<64;j++) acc[j] = fmaf(hv, w2[c*OUT_CH + d0 + j], acc[j]);
  }
  float* ob = out + (size_t)b*OUT_CH*SP + (size_t)d0*SP + p;
  #pragma unroll
  for (int j=0;j<64;j++) ob[(size_t)j*SP] = acc[j];
}

extern "C" void kernel_launch(void* const* d_in, const int* in_sizes, int n_in,
                              void* d_out, int out_size, void* d_ws, size_t ws_size,
                              hipStream_t stream)
{
  const float* x   = (const float*)d_in[0];
  const float* w1  = (const float*)d_in[1];
  const float* b1  = (const float*)d_in[2];
  const float* gp  = (const float*)d_in[3];
  const float* bp  = (const float*)d_in[4];
  const float* Wip = (const float*)d_in[5];
  const float* bip = (const float*)d_in[6];
  const float* gn  = (const float*)d_in[7];
  const float* bnl = (const float*)d_in[8];
  const float* Win = (const float*)d_in[9];
  const float* bin = (const float*)d_in[10];
  const float* cb  = (const float*)d_in[11];
  const float* Wop = (const float*)d_in[12];
  const float* bop = (const float*)d_in[13];
  const float* Won = (const float*)d_in[14];
  const float* bon = (const float*)d_in[15];
  const float* w2  = (const float*)d_in[16];
  const float* b2  = (const float*)d_in[17];
  float* out = (float*)d_out;
  float* ws  = (float*)d_ws;

  float* h    = ws;                                  // 2,097,152 f
  __hip_bfloat16* Ahi = (__hip_bfloat16*)(ws + 2097152);  // 2,097,152 bf16 (1,048,576 f)
  __hip_bfloat16* Alo = (__hip_bfloat16*)(ws + 3145728);  // 1,048,576 f
  float* z    = ws + 4194304;                        // 524,288 f
  __hip_bfloat16* zqA = (__hip_bfloat16*)(ws + 4718592);  // 524,288 bf16 (262,144 f)
  float* cc   = ws + 4980736;                        // 1,024 f
  float* sse  = ws + 4981760;                        // 8,192 f
  float* bests= ws + 4989952;                        // 131,072 f
  int*   bestj= (int*)(ws + 5121024);                // 131,072
  float* part = ws + 5252096;                        // up to 8,388,608 f

  size_t wsf = ws_size/4;
  int KCe=16, KCd=4;
  if (wsf < (size_t)5252096 + 8388608) { KCe=8; KCd=2; }
  if (wsf < (size_t)5252096 + 4194304) { KCe=4; KCd=1; }

  k_conv_in<<<dim3(64,2),256,0,stream>>>(x,w1,b1,h);
  k_stats_build<<<128,256,0,stream>>>(h,gp,bp,gn,bnl,Ahi,Alo);
  k_gemm_mfma<4096,16384,3><<<dim3(32,KCe,2),256,0,stream>>>(Ahi,Alo,Wip,Win,part,16384/KCe,KCe);
  k_zreduce<<<2048,256,0,stream>>>(part,bip,bin,z,KCe);
  k_cc<<<4,256,0,stream>>>(cb,cc);
  k_qscan<<<dim3(32,16),256,0,stream>>>(z,cb,cc,bests,bestj);
  k_qfin<<<32,256,0,stream>>>(z,cb,bests,bestj,zqA,sse);
  k_gemm_mfma<16384,4096,1><<<dim3(128,KCd,2),256,0,stream>>>(zqA,zqA,Wop,Won,part,4096/KCd,KCd);
  k_hreduce<<<8192,256,0,stream>>>(part,bop,bon,h,KCd);
  k_conv_out<<<dim3(64,4),256,0,stream>>>(h,w2,b2,out);
  k_loss<<<1,256,0,stream>>>(sse,out);
}

// Round 4
// 568.294 us; speedup vs baseline: 2.5624x; 1.0711x over previous
//
#include <hip/hip_runtime.h>
#include <hip/hip_bf16.h>
#include <math.h>

#define BB 64
#define IN_CH 256
#define CH 128
#define OUT_CH 256
#define SP 256        // RES*RES
#define EMBED 64
#define N_EMBED 1024
#define NPH 64
#define FLAT_IN 16384
#define FLAT_Z 4096

typedef short bf16x8 __attribute__((ext_vector_type(8)));
typedef float f32x4 __attribute__((ext_vector_type(4)));

__device__ __forceinline__ float silu_f(float x){ return x / (1.0f + expf(-x)); }

__device__ __forceinline__ void gl_lds16(const float* g, float* l){
  __builtin_amdgcn_global_load_lds(
      (const __attribute__((address_space(1))) void*)g,
      (__attribute__((address_space(3))) void*)l, 16, 0, 0);
}

// ---- fused conv_in(1x1)+silu + LN stats(fp64) + LN apply + bf16 hi/lo split
// block=(b,half): computes h[b][half*64..+64][256p] in regs, then Ahi/Alo[ws*64+b][16384]
__global__ __launch_bounds__(256) void k_fused_in(const float* __restrict__ x,
    const float* __restrict__ w1, const float* __restrict__ b1,
    const float* __restrict__ gp, const float* __restrict__ bp,
    const float* __restrict__ gn, const float* __restrict__ bnl,
    __hip_bfloat16* __restrict__ Ahi, __hip_bfloat16* __restrict__ Alo)
{
  int b = blockIdx.x, ws = blockIdx.y;
  int t = threadIdx.x;            // = spatial p
  int d0 = ws*64;
  float acc[64];
  #pragma unroll
  for (int j=0;j<64;j++) acc[j] = b1[d0+j];
  const float* xb = x + (size_t)b*IN_CH*SP + t;
  for (int c=0;c<IN_CH;c++){
    float xv = xb[(size_t)c*SP];
    #pragma unroll
    for (int j=0;j<64;j++) acc[j] = fmaf(xv, w1[c*CH + d0 + j], acc[j]);
  }
  // silu + fp64 partial stats
  double s1=0.0, s2=0.0;
  #pragma unroll
  for (int j=0;j<64;j++){
    float v = silu_f(acc[j]);
    acc[j] = v;
    double dv = (double)v;
    s1 += dv; s2 += dv*dv;
  }
  __shared__ double l1[256], l2[256];
  l1[t]=s1; l2[t]=s2; __syncthreads();
  for (int s=128; s>0; s>>=1){
    if (t<s){ l1[t]+=l1[t+s]; l2[t]+=l2[t+s]; }
    __syncthreads();
  }
  double m = l1[0]/(double)FLAT_IN;
  double v = l2[0]/(double)FLAT_IN - m*m;
  float mf = (float)m;
  float rs = (float)(1.0/sqrt(v+1e-5));
  const float* g  = ws? gn : gp;
  const float* bb = ws? bnl: bp;
  __hip_bfloat16* oh = Ahi + ((size_t)ws*64 + b)*FLAT_IN;
  __hip_bfloat16* ol = Alo + ((size_t)ws*64 + b)*FLAT_IN;
  #pragma unroll 4
  for (int j=0;j<64;j++){
    int k = j*256 + t;
    float val = fmaf((acc[j]-mf)*rs, g[k], bb[k]);
    __hip_bfloat16 hb = __float2bfloat16(val);
    oh[k] = hb;
    ol[k] = __float2bfloat16(val - __bfloat162float(hb));
  }
}

// ---- streaming MFMA split-K GEMM, M=64.
// A: bf16 m-major [ws*64+m][K] (hi, +lo if PASSES==2). W: fp32 [K][N] staged to LDS.
// part[(wsel*KC+kc)*64 + m][N]
template<int N, int K, int PASSES>
__global__ __launch_bounds__(256) void k_gemm_mfma(
    const __hip_bfloat16* __restrict__ Ahi, const __hip_bfloat16* __restrict__ Alo,
    const float* __restrict__ W0, const float* __restrict__ W1,
    float* __restrict__ part, int CHUNK, int KC)
{
  __shared__ float wlds[2*4096];   // 2 x (32k x 128n) fp32 = 32KB
  int nt = blockIdx.x, kc = blockIdx.y, wsel = blockIdx.z;
  const float* W = wsel ? W1 : W0;
  int t = threadIdx.x;
  int wave = t >> 6, lane = t & 63;
  int rl = lane & 15;
  int g  = lane >> 4;              // 0..3 (k-group)
  int kg = g * 8;
  int nbase = nt*128;
  int k0 = kc*CHUNK;

  const __hip_bfloat16* Ah = Ahi + (size_t)wsel*64*K;
  const __hip_bfloat16* Al = (PASSES==2) ? (Alo + (size_t)wsel*64*K) : Ah;

  // swizzle s(k) = ((k>>3)&1)<<4 | ((k>>3)&2)<<1  (in {0,16,4,20})
  int s_lane = ((g&1)<<4) | ((g&2)<<1);
  int wbase0 = kg*128 + ((wave*32 + rl) ^ s_lane);
  int wbase1 = kg*128 + ((wave*32 + 16 + rl) ^ s_lane);

  // stage: dest float idx fi = (i*4+wave)*256 + lane*4 (linear); src col pre-swizzled
  int src_off[4]; int dst_base[4];
  #pragma unroll
  for (int i=0;i<4;i++){
    int fi = (i*4+wave)*256 + lane*4;
    int kl = fi>>7, nn = fi&127;
    int s = (((kl>>3)&1)<<4) | (((kl>>3)&2)<<1);
    src_off[i] = kl*N + nbase + (nn ^ s);
    dst_base[i] = (i*4+wave)*256;           // wave-uniform
  }

  f32x4 acc[4][2];
  #pragma unroll
  for (int mf=0; mf<4; ++mf){ acc[mf][0] = (f32x4){0,0,0,0}; acc[mf][1] = (f32x4){0,0,0,0}; }

  auto STAGE = [&](int buf, int ks){
    const float* Wr = W + (size_t)(k0 + ks*32)*N;
    float* lb = &wlds[buf*4096];
    #pragma unroll
    for (int i=0;i<4;i++) gl_lds16(Wr + src_off[i], lb + dst_base[i]);
  };

  int NT = CHUNK/32;
  STAGE(0, 0);

  for (int ks=0; ks<NT; ++ks){
    int cur = ks & 1;
    int ksn = (ks+1 < NT) ? ks+1 : ks;
    STAGE(cur^1, ksn);
    // A-fragment loads (global, L2-resident); compiler inserts waits for reg deps
    bf16x8 ah[4], al[4];
    {
      size_t ko = (size_t)k0 + (size_t)ks*32 + kg;
      #pragma unroll
      for (int mf=0; mf<4; ++mf){
        ah[mf] = *(const bf16x8*)(Ah + ((size_t)(mf*16+rl))*K + ko);
        if (PASSES==2) al[mf] = *(const bf16x8*)(Al + ((size_t)(mf*16+rl))*K + ko);
      }
    }
    __builtin_amdgcn_sched_barrier(0);
    if (PASSES==2) { asm volatile("s_waitcnt vmcnt(12)" ::: "memory"); }
    else           { asm volatile("s_waitcnt vmcnt(8)"  ::: "memory"); }
    __builtin_amdgcn_s_barrier();          // all waves' cur-stage complete
    __builtin_amdgcn_sched_barrier(0);

    // W fragments from LDS (2-way bank aliasing only)
    const float* lb = &wlds[cur*4096];
    float wv0[8], wv1[8];
    #pragma unroll
    for (int j=0;j<8;j++){ wv0[j] = lb[wbase0 + j*128]; wv1[j] = lb[wbase1 + j*128]; }
    bf16x8 bh[2];
    #pragma unroll
    for (int j=0;j<8;j++){
      bh[0][j] = __builtin_bit_cast(short, __float2bfloat16(wv0[j]));
      bh[1][j] = __builtin_bit_cast(short, __float2bfloat16(wv1[j]));
    }
    #pragma unroll
    for (int mf=0; mf<4; ++mf){
      acc[mf][0] = __builtin_amdgcn_mfma_f32_16x16x32_bf16(ah[mf], bh[0], acc[mf][0], 0,0,0);
      acc[mf][1] = __builtin_amdgcn_mfma_f32_16x16x32_bf16(ah[mf], bh[1], acc[mf][1], 0,0,0);
    }
    if (PASSES==2){
      #pragma unroll
      for (int mf=0; mf<4; ++mf){
        acc[mf][0] = __builtin_amdgcn_mfma_f32_16x16x32_bf16(al[mf], bh[0], acc[mf][0], 0,0,0);
        acc[mf][1] = __builtin_amdgcn_mfma_f32_16x16x32_bf16(al[mf], bh[1], acc[mf][1], 0,0,0);
      }
    }
    __builtin_amdgcn_s_barrier();          // reads of cur done before it is re-staged
    __builtin_amdgcn_sched_barrier(0);
  }

  float* P = part + ((size_t)((wsel*KC + kc)*64))*N + nbase + wave*32 + rl;
  #pragma unroll
  for (int mf=0; mf<4; ++mf)
    #pragma unroll
    for (int f=0; f<2; ++f)
      #pragma unroll
      for (int r=0; r<4; ++r)
        P[((size_t)(mf*16 + g*4 + r))*N + f*16] = acc[mf][f][r];
}

// ---- z = sum partials + bias; z[ws][m][4096]
__global__ __launch_bounds__(256) void k_zreduce(const float* __restrict__ part,
  const float* __restrict__ bp, const float* __restrict__ bn,
  float* __restrict__ z, int KC)
{
  int idx = blockIdx.x*256 + threadIdx.x;     // < 2*64*4096
  int ws = idx >> 18; int rem = idx & 262143;
  int m = rem >> 12; int n = rem & 4095;
  float s = (ws? bn: bp)[n];
  const float* p = part + ((size_t)ws*KC*64 + m)*4096 + n;
  for (int kc=0;kc<KC;kc++) s += p[(size_t)kc*64*4096];
  z[idx] = s;
}

// ---- argmin scan over a 64-code split; score s = cc[j] - 2*z.c[j]  (cc inline)
__global__ __launch_bounds__(256) void k_qscan(const float* __restrict__ z,
  const float* __restrict__ cb,
  float* __restrict__ bests, int* __restrict__ bestj)
{
  int r = blockIdx.x*256 + threadIdx.x;   // < 8192
  int cs = blockIdx.y;                    // 16 splits of 64 codes
  int ws = r>>12, rem = r&4095; int b = rem>>6, rr = rem&63;
  const float* zr = z + (size_t)ws*BB*FLAT_Z + (size_t)b*FLAT_Z + rr;
  float zr_[EMBED];
  #pragma unroll
  for (int e=0;e<EMBED;e++) zr_[e] = zr[(size_t)e*64];
  float best = 3.4e38f; int bj = 0;
  int j0 = cs*64;
  for (int jj=0;jj<64;jj++){
    int j = j0 + jj;
    const float* c = cb + (size_t)j*EMBED;
    float cc = 0.f;
    #pragma unroll
    for (int e=0;e<EMBED;e++){ float cv = c[e]; cc = fmaf(cv,cv,cc); }
    float s1 = 0.f;
    #pragma unroll
    for (int e=0;e<EMBED;e++) s1 = fmaf(c[e], zr_[e], s1);
    float s = fmaf(-2.f, s1, cc);
    if (s < best){ best = s; bj = j; }   // strict < : first-index semantics
  }
  bests[(size_t)cs*8192 + r] = best;
  bestj[(size_t)cs*8192 + r] = bj;
}

// ---- finalize: combine splits, write zqA bf16 [ws*64+b][4096], row sse
__global__ __launch_bounds__(256) void k_qfin(const float* __restrict__ z,
  const float* __restrict__ cb, const float* __restrict__ bests, const int* __restrict__ bestj,
  __hip_bfloat16* __restrict__ zqA, float* __restrict__ row_sse)
{
  int r = blockIdx.x*256 + threadIdx.x;
  float best = 3.4e38f; int bj = 0;
  for (int cs=0;cs<16;cs++){              // ascending code ranges
    float v = bests[(size_t)cs*8192 + r];
    int j = bestj[(size_t)cs*8192 + r];
    if (v < best){ best=v; bj=j; }
  }
  int ws = r>>12, rem = r&4095; int b = rem>>6, rr = rem&63;
  const float* zr = z + (size_t)ws*BB*FLAT_Z + (size_t)b*FLAT_Z + rr;
  const float* c = cb + (size_t)bj*EMBED;
  __hip_bfloat16* zq = zqA + ((size_t)ws*64 + b)*FLAT_Z;
  float sse = 0.f;
  #pragma unroll
  for (int e=0;e<EMBED;e++){
    float cv = c[e];
    float zv = zr[(size_t)e*64];
    float d = cv - zv; sse = fmaf(d,d,sse);
    zq[(size_t)e*64 + rr] = __float2bfloat16(cv);
  }
  row_sse[r] = sse;
}

// ---- loss reduce (deterministic, fp64)
__global__ __launch_bounds__(256) void k_loss(const float* __restrict__ row_sse, float* __restrict__ out){
  __shared__ double l[256];
  double s=0.0;
  for (int i=threadIdx.x;i<8192;i+=256) s += (double)row_sse[i];
  l[threadIdx.x]=s; __syncthreads();
  for (int st=128;st>0;st>>=1){ if (threadIdx.x<st) l[threadIdx.x]+=l[threadIdx.x+st]; __syncthreads(); }
  if (threadIdx.x==0) out[(size_t)BB*OUT_CH*SP] = (float)(l[0]*1.25/262144.0);
}

// ---- hout reduce + bias -> h_[m][128][256]
__global__ __launch_bounds__(256) void k_hreduce(const float* __restrict__ part,
  const float* __restrict__ bp, const float* __restrict__ bn,
  float* __restrict__ hbuf, int KC)
{
  int idx = blockIdx.x*256 + threadIdx.x;  // < 2*64*16384
  int ws = idx >> 20; int rem = idx & 1048575;
  int m = rem >> 14; int n = rem & 16383;
  float s = (ws? bn: bp)[n];
  const float* p = part + ((size_t)ws*KC*64 + m)*16384 + n;
  for (int kc=0;kc<KC;kc++) s += p[(size_t)kc*64*16384];
  hbuf[((size_t)m*CH + ws*NPH + (n>>8))*SP + (n&255)] = s;
}

// ---- conv_out (silu on input) -> d_out; dg<4, 64 d each
__global__ __launch_bounds__(256) void k_conv_out(const float* __restrict__ hbuf,
  const float* __restrict__ w2, const float* __restrict__ b2, float* __restrict__ out)
{
  int b = blockIdx.x, dg = blockIdx.y;
  int p = threadIdx.x;
  int d0 = dg*64;
  float acc[64];
  #pragma unroll
  for (int j=0;j<64;j++) acc[j]=b2[d0+j];
  const float* hb = hbuf + (size_t)b*CH*SP + p;
  for (int c=0;c<CH;c++){
    float hv = silu_f(hb[(size_t)c*SP]);
    #pragma unroll
    for (int j=0;j<64;j++) acc[j] = fmaf(hv, w2[c*OUT_CH + d0 + j], acc[j]);
  }
  float* ob = out + (size_t)b*OUT_CH*SP + (size_t)d0*SP + p;
  #pragma unroll
  for (int j=0;j<64;j++) ob[(size_t)j*SP] = acc[j];
}

extern "C" void kernel_launch(void* const* d_in, const int* in_sizes, int n_in,
                              void* d_out, int out_size, void* d_ws, size_t ws_size,
                              hipStream_t stream)
{
  const float* x   = (const float*)d_in[0];
  const float* w1  = (const float*)d_in[1];
  const float* b1  = (const float*)d_in[2];
  const float* gp  = (const float*)d_in[3];
  const float* bp  = (const float*)d_in[4];
  const float* Wip = (const float*)d_in[5];
  const float* bip = (const float*)d_in[6];
  const float* gn  = (const float*)d_in[7];
  const float* bnl = (const float*)d_in[8];
  const float* Win = (const float*)d_in[9];
  const float* bin = (const float*)d_in[10];
  const float* cb  = (const float*)d_in[11];
  const float* Wop = (const float*)d_in[12];
  const float* bop = (const float*)d_in[13];
  const float* Won = (const float*)d_in[14];
  const float* bon = (const float*)d_in[15];
  const float* w2  = (const float*)d_in[16];
  const float* b2  = (const float*)d_in[17];
  float* out = (float*)d_out;
  float* ws  = (float*)d_ws;

  __hip_bfloat16* Ahi = (__hip_bfloat16*)ws;               // 1,048,576 f
  __hip_bfloat16* Alo = (__hip_bfloat16*)(ws + 1048576);   // 1,048,576 f
  float* z    = ws + 2097152;                              // 524,288 f
  __hip_bfloat16* zqA = (__hip_bfloat16*)(ws + 2621440);   // 262,144 f
  float* hh   = ws + 2883584;                              // 2,097,152 f
  float* sse  = ws + 4980736;                              // 8,192 f
  float* bests= ws + 4988928;                              // 131,072 f
  int*   bestj= (int*)(ws + 5120000);                      // 131,072
  float* part = ws + 5251072;                              // up to 8,388,608 f

  size_t wsf = ws_size/4;
  int KCe=16, KCd=4;
  if (wsf < (size_t)5251072 + 8388608) { KCe=8; KCd=2; }
  if (wsf < (size_t)5251072 + 4194304) { KCe=4; KCd=1; }

  k_fused_in<<<dim3(64,2),256,0,stream>>>(x,w1,b1,gp,bp,gn,bnl,Ahi,Alo);
  k_gemm_mfma<4096,16384,2><<<dim3(32,KCe,2),256,0,stream>>>(Ahi,Alo,Wip,Win,part,16384/KCe,KCe);
  k_zreduce<<<2048,256,0,stream>>>(part,bip,bin,z,KCe);
  k_qscan<<<dim3(32,16),256,0,stream>>>(z,cb,bests,bestj);
  k_qfin<<<32,256,0,stream>>>(z,cb,bests,bestj,zqA,sse);
  k_gemm_mfma<16384,4096,1><<<dim3(128,KCd,2),256,0,stream>>>(zqA,zqA,Wop,Won,part,4096/KCd,KCd);
  k_hreduce<<<8192,256,0,stream>>>(part,bop,bon,hh,KCd);
  k_conv_out<<<dim3(64,4),256,0,stream>>>(hh,w2,b2,out);
  k_loss<<<1,256,0,stream>>>(sse,out);
}

// Round 5
// 483.141 us; speedup vs baseline: 3.0140x; 1.1762x over previous
//
#include <hip/hip_runtime.h>
#include <hip/hip_bf16.h>
#include <math.h>

#define BB 64
#define IN_CH 256
#define CH 128
#define OUT_CH 256
#define SP 256        // RES*RES
#define EMBED 64
#define N_EMBED 1024
#define NPH 64
#define FLAT_IN 16384
#define FLAT_Z 4096

typedef short bf16x8 __attribute__((ext_vector_type(8)));
typedef float f32x4 __attribute__((ext_vector_type(4)));

__device__ __forceinline__ float silu_f(float x){ return x / (1.0f + expf(-x)); }

__device__ __forceinline__ void gl_lds16(const void* g, void* l){
  __builtin_amdgcn_global_load_lds(
      (const __attribute__((address_space(1))) void*)g,
      (__attribute__((address_space(3))) void*)l, 16, 0, 0);
}

// ---- fused conv_in(1x1)+silu + LN stats(fp64) + LN apply + bf16
// block=(b,half): h[b][half*64..+64][256p] in regs -> Ahi[ws*64+b][16384] bf16
__global__ __launch_bounds__(256) void k_fused_in(const float* __restrict__ x,
    const float* __restrict__ w1, const float* __restrict__ b1,
    const float* __restrict__ gp, const float* __restrict__ bp,
    const float* __restrict__ gn, const float* __restrict__ bnl,
    __hip_bfloat16* __restrict__ Ahi)
{
  int b = blockIdx.x, ws = blockIdx.y;
  int t = threadIdx.x;            // = spatial p
  int d0 = ws*64;
  float acc[64];
  #pragma unroll
  for (int j=0;j<64;j++) acc[j] = b1[d0+j];
  const float* xb = x + (size_t)b*IN_CH*SP + t;
  for (int c=0;c<IN_CH;c++){
    float xv = xb[(size_t)c*SP];
    #pragma unroll
    for (int j=0;j<64;j++) acc[j] = fmaf(xv, w1[c*CH + d0 + j], acc[j]);
  }
  double s1=0.0, s2=0.0;
  #pragma unroll
  for (int j=0;j<64;j++){
    float v = silu_f(acc[j]);
    acc[j] = v;
    double dv = (double)v;
    s1 += dv; s2 += dv*dv;
  }
  __shared__ double l1[256], l2[256];
  l1[t]=s1; l2[t]=s2; __syncthreads();
  for (int s=128; s>0; s>>=1){
    if (t<s){ l1[t]+=l1[t+s]; l2[t]+=l2[t+s]; }
    __syncthreads();
  }
  double m = l1[0]/(double)FLAT_IN;
  double v = l2[0]/(double)FLAT_IN - m*m;
  float mf = (float)m;
  float rs = (float)(1.0/sqrt(v+1e-5));
  const float* g  = ws? gn : gp;
  const float* bb = ws? bnl: bp;
  __hip_bfloat16* oh = Ahi + ((size_t)ws*64 + b)*FLAT_IN;
  #pragma unroll 4
  for (int j=0;j<64;j++){
    int k = j*256 + t;
    float val = fmaf((acc[j]-mf)*rs, g[k], bb[k]);
    oh[k] = __float2bfloat16(val);
  }
}

// ---- streaming bf16 MFMA split-K GEMM, M=64, depth-1 pipelined via counted vmcnt.
// A: bf16 m-major [2][64][K]. W: fp32 [K][N], staged to LDS (16KB) + A tile (4KB).
// part[(wsel*KC+kc)*64 + m][N]
template<int N, int K>
__global__ __launch_bounds__(256) void k_gemm_mfma(
    const __hip_bfloat16* __restrict__ A,
    const float* __restrict__ W0, const float* __restrict__ W1,
    float* __restrict__ part, int CHUNK, int KC)
{
  __shared__ float wlds[2*4096];   // 2 x (32k x 128n) fp32
  __shared__ float alds[2*1024];   // 2 x (64m x 32k) bf16
  int nt = blockIdx.x, kc = blockIdx.y, wsel = blockIdx.z;
  const float* W = wsel ? W1 : W0;
  int t = threadIdx.x;
  int wave = t >> 6, lane = t & 63;
  int rl = lane & 15;
  int g  = lane >> 4;              // 0..3 (k-group)
  int kg = g * 8;
  int nbase = nt*128;
  int k0 = kc*CHUNK;

  const __hip_bfloat16* Aw = A + (size_t)wsel*64*K;

  // W LDS swizzle: s(kl) = ((kl>>3)&1)<<4 | ((kl>>3)&2)<<1
  int s_lane = ((g&1)<<4) | ((g&2)<<1);
  int wbase0 = kg*128 + ((wave*32 + rl) ^ s_lane);
  int wbase1 = kg*128 + ((wave*32 + 16 + rl) ^ s_lane);
  // A read byte offset within buffer: row m=mf*16+rl (64B), col16 = g ^ ((rl>>1)&3)
  int abyte[4];
  #pragma unroll
  for (int mf=0; mf<4; ++mf)
    abyte[mf] = (mf*16+rl)*64 + ((g ^ ((rl>>1)&3))<<4);

  // W stage: dest linear, source col pre-swizzled
  int src_off[4]; int dst_base[4];
  #pragma unroll
  for (int i=0;i<4;i++){
    int fi = (i*4+wave)*256 + lane*4;
    int kl = fi>>7, nn = fi&127;
    int s = (((kl>>3)&1)<<4) | (((kl>>3)&2)<<1);
    src_off[i] = kl*N + nbase + (nn ^ s);
    dst_base[i] = (i*4+wave)*256;           // wave-uniform
  }
  // A stage: thread t writes LDS bytes t*16 (m=t>>2, col16=t&3); source k-quad swizzled
  size_t a_src = (size_t)(t>>2)*K + (size_t)(((t&3)^((t>>3)&3))*8);
  int a_dst = wave*256;                     // floats, wave-uniform

  f32x4 acc[4][2];
  #pragma unroll
  for (int mf=0; mf<4; ++mf){ acc[mf][0] = (f32x4){0,0,0,0}; acc[mf][1] = (f32x4){0,0,0,0}; }

  auto STAGE = [&](int buf, int ks){
    const float* Wr = W + (size_t)(k0 + ks*32)*N;
    float* lb = &wlds[buf*4096];
    #pragma unroll
    for (int i=0;i<4;i++) gl_lds16(Wr + src_off[i], lb + dst_base[i]);
    gl_lds16(Aw + a_src + (size_t)(k0 + ks*32), &alds[buf*1024] + a_dst);
  };

  int NT_ = CHUNK/32;
  STAGE(0, 0);

  for (int ks=0; ks<NT_; ++ks){
    int cur = ks & 1;
    int ksn = (ks+1 < NT_) ? ks+1 : ks;
    STAGE(cur^1, ksn);                      // 5 loads stay in flight across compute
    __builtin_amdgcn_sched_barrier(0);
    asm volatile("s_waitcnt vmcnt(5)" ::: "memory");   // cur tile complete, next in flight
    __builtin_amdgcn_s_barrier();
    __builtin_amdgcn_sched_barrier(0);

    const float* lb = &wlds[cur*4096];
    const char* ab = (const char*)&alds[cur*1024];
    bf16x8 ah[4];
    #pragma unroll
    for (int mf=0; mf<4; ++mf) ah[mf] = *(const bf16x8*)(ab + abyte[mf]);
    float wv0[8], wv1[8];
    #pragma unroll
    for (int j=0;j<8;j++){ wv0[j] = lb[wbase0 + j*128]; wv1[j] = lb[wbase1 + j*128]; }
    bf16x8 bh0, bh1;
    #pragma unroll
    for (int j=0;j<8;j++){
      bh0[j] = __builtin_bit_cast(short, __float2bfloat16(wv0[j]));
      bh1[j] = __builtin_bit_cast(short, __float2bfloat16(wv1[j]));
    }
    #pragma unroll
    for (int mf=0; mf<4; ++mf){
      acc[mf][0] = __builtin_amdgcn_mfma_f32_16x16x32_bf16(ah[mf], bh0, acc[mf][0], 0,0,0);
      acc[mf][1] = __builtin_amdgcn_mfma_f32_16x16x32_bf16(ah[mf], bh1, acc[mf][1], 0,0,0);
    }
    __builtin_amdgcn_sched_barrier(0);
    __builtin_amdgcn_s_barrier();           // all reads of cur done before it is re-staged
  }
  asm volatile("s_waitcnt vmcnt(0)" ::: "memory");  // drain trailing stage before exit

  float* P = part + ((size_t)((wsel*KC + kc)*64))*N + nbase + wave*32 + rl;
  #pragma unroll
  for (int mf=0; mf<4; ++mf)
    #pragma unroll
    for (int f=0; f<2; ++f)
      #pragma unroll
      for (int r=0; r<4; ++r)
        P[((size_t)(mf*16 + g*4 + r))*N + f*16] = acc[mf][f][r];
}

// ---- z = sum partials + bias; z[ws][m][4096]
__global__ __launch_bounds__(256) void k_zreduce(const float* __restrict__ part,
  const float* __restrict__ bp, const float* __restrict__ bn,
  float* __restrict__ z, int KC)
{
  int idx = blockIdx.x*256 + threadIdx.x;     // < 2*64*4096
  int ws = idx >> 18; int rem = idx & 262143;
  int m = rem >> 12; int n = rem & 4095;
  float s = (ws? bn: bp)[n];
  const float* p = part + ((size_t)ws*KC*64 + m)*4096 + n;
  for (int kc=0;kc<KC;kc++) s += p[(size_t)kc*64*4096];
  z[idx] = s;
}

// ---- codebook squared norms
__global__ __launch_bounds__(256) void k_cc(const float* __restrict__ cb, float* __restrict__ cc){
  int j = blockIdx.x*256 + threadIdx.x;
  if (j >= N_EMBED) return;
  float s=0.f;
  for (int e=0;e<EMBED;e++){ float c = cb[(size_t)j*EMBED+e]; s = fmaf(c,c,s); }
  cc[j]=s;
}

// ---- argmin scan over a 64-code split; score s = cc[j] - 2*z.c[j]
__global__ __launch_bounds__(256) void k_qscan(const float* __restrict__ z,
  const float* __restrict__ cb, const float* __restrict__ cc,
  float* __restrict__ bests, int* __restrict__ bestj)
{
  int r = blockIdx.x*256 + threadIdx.x;   // < 8192
  int cs = blockIdx.y;                    // 16 splits of 64 codes
  int ws = r>>12, rem = r&4095; int b = rem>>6, rr = rem&63;
  const float* zr = z + (size_t)ws*BB*FLAT_Z + (size_t)b*FLAT_Z + rr;
  float zr_[EMBED];
  #pragma unroll
  for (int e=0;e<EMBED;e++) zr_[e] = zr[(size_t)e*64];
  float best = 3.4e38f; int bj = 0;
  int j0 = cs*64;
  for (int jj=0;jj<64;jj++){
    int j = j0 + jj;
    const float* c = cb + (size_t)j*EMBED;
    float s1 = 0.f;
    #pragma unroll
    for (int e=0;e<EMBED;e++) s1 = fmaf(c[e], zr_[e], s1);
    float s = fmaf(-2.f, s1, cc[j]);
    if (s < best){ best = s; bj = j; }   // strict < : first-index semantics
  }
  bests[(size_t)cs*8192 + r] = best;
  bestj[(size_t)cs*8192 + r] = bj;
}

// ---- finalize: combine splits, write zqA bf16 [ws*64+b][4096], row sse
__global__ __launch_bounds__(256) void k_qfin(const float* __restrict__ z,
  const float* __restrict__ cb, const float* __restrict__ bests, const int* __restrict__ bestj,
  __hip_bfloat16* __restrict__ zqA, float* __restrict__ row_sse)
{
  int r = blockIdx.x*256 + threadIdx.x;
  float best = 3.4e38f; int bj = 0;
  for (int cs=0;cs<16;cs++){              // ascending code ranges
    float v = bests[(size_t)cs*8192 + r];
    int j = bestj[(size_t)cs*8192 + r];
    if (v < best){ best=v; bj=j; }
  }
  int ws = r>>12, rem = r&4095; int b = rem>>6, rr = rem&63;
  const float* zr = z + (size_t)ws*BB*FLAT_Z + (size_t)b*FLAT_Z + rr;
  const float* c = cb + (size_t)bj*EMBED;
  __hip_bfloat16* zq = zqA + ((size_t)ws*64 + b)*FLAT_Z;
  float sse = 0.f;
  #pragma unroll
  for (int e=0;e<EMBED;e++){
    float cv = c[e];
    float zv = zr[(size_t)e*64];
    float d = cv - zv; sse = fmaf(d,d,sse);
    zq[(size_t)e*64 + rr] = __float2bfloat16(cv);
  }
  row_sse[r] = sse;
}

// ---- loss reduce (deterministic, fp64)
__global__ __launch_bounds__(256) void k_loss(const float* __restrict__ row_sse, float* __restrict__ out){
  __shared__ double l[256];
  double s=0.0;
  for (int i=threadIdx.x;i<8192;i+=256) s += (double)row_sse[i];
  l[threadIdx.x]=s; __syncthreads();
  for (int st=128;st>0;st>>=1){ if (threadIdx.x<st) l[threadIdx.x]+=l[threadIdx.x+st]; __syncthreads(); }
  if (threadIdx.x==0) out[(size_t)BB*OUT_CH*SP] = (float)(l[0]*1.25/262144.0);
}

// ---- hout reduce + bias -> h_[m][128][256]
__global__ __launch_bounds__(256) void k_hreduce(const float* __restrict__ part,
  const float* __restrict__ bp, const float* __restrict__ bn,
  float* __restrict__ hbuf, int KC)
{
  int idx = blockIdx.x*256 + threadIdx.x;  // < 2*64*16384
  int ws = idx >> 20; int rem = idx & 1048575;
  int m = rem >> 14; int n = rem & 16383;
  float s = (ws? bn: bp)[n];
  const float* p = part + ((size_t)ws*KC*64 + m)*16384 + n;
  for (int kc=0;kc<KC;kc++) s += p[(size_t)kc*64*16384];
  hbuf[((size_t)m*CH + ws*NPH + (n>>8))*SP + (n&255)] = s;
}

// ---- conv_out (silu on input) -> d_out; dg<4, 64 d each
__global__ __launch_bounds__(256) void k_conv_out(const float* __restrict__ hbuf,
  const float* __restrict__ w2, const float* __restrict__ b2, float* __restrict__ out)
{
  int b = blockIdx.x, dg = blockIdx.y;
  int p = threadIdx.x;
  int d0 = dg*64;
  float acc[64];
  #pragma unroll
  for (int j=0;j<64;j++) acc[j]=b2[d0+j];
  const float* hb = hbuf + (size_t)b*CH*SP + p;
  for (int c=0;c<CH;c++){
    float hv = silu_f(hb[(size_t)c*SP]);
    #pragma unroll
    for (int j=0;j<64;j++) acc[j] = fmaf(hv, w2[c*OUT_CH + d0 + j], acc[j]);
  }
  float* ob = out + (size_t)b*OUT_CH*SP + (size_t)d0*SP + p;
  #pragma unroll
  for (int j=0;j<64;j++) ob[(size_t)j*SP] = acc[j];
}

extern "C" void kernel_launch(void* const* d_in, const int* in_sizes, int n_in,
                              void* d_out, int out_size, void* d_ws, size_t ws_size,
                              hipStream_t stream)
{
  const float* x   = (const float*)d_in[0];
  const float* w1  = (const float*)d_in[1];
  const float* b1  = (const float*)d_in[2];
  const float* gp  = (const float*)d_in[3];
  const float* bp  = (const float*)d_in[4];
  const float* Wip = (const float*)d_in[5];
  const float* bip = (const float*)d_in[6];
  const float* gn  = (const float*)d_in[7];
  const float* bnl = (const float*)d_in[8];
  const float* Win = (const float*)d_in[9];
  const float* bin = (const float*)d_in[10];
  const float* cb  = (const float*)d_in[11];
  const float* Wop = (const float*)d_in[12];
  const float* bop = (const float*)d_in[13];
  const float* Won = (const float*)d_in[14];
  const float* bon = (const float*)d_in[15];
  const float* w2  = (const float*)d_in[16];
  const float* b2  = (const float*)d_in[17];
  float* out = (float*)d_out;
  float* ws  = (float*)d_ws;

  __hip_bfloat16* Ahi = (__hip_bfloat16*)ws;               // 1,048,576 f
  float* z    = ws + 1048576;                              // 524,288 f
  __hip_bfloat16* zqA = (__hip_bfloat16*)(ws + 1572864);   // 262,144 f
  float* hh   = ws + 1835008;                              // 2,097,152 f
  float* cc   = ws + 3932160;                              // 1,024 f
  float* sse  = ws + 3933184;                              // 8,192 f
  float* bests= ws + 3941376;                              // 131,072 f
  int*   bestj= (int*)(ws + 4072448);                      // 131,072
  float* part = ws + 4203520;                              // up to 8,388,608 f

  size_t wsf = ws_size/4;
  int KCe=16, KCd=4;
  if (wsf < (size_t)4203520 + 8388608) { KCe=8; KCd=2; }
  if (wsf < (size_t)4203520 + 4194304) { KCe=4; KCd=1; }

  k_fused_in<<<dim3(64,2),256,0,stream>>>(x,w1,b1,gp,bp,gn,bnl,Ahi);
  k_gemm_mfma<4096,16384><<<dim3(32,KCe,2),256,0,stream>>>(Ahi,Wip,Win,part,16384/KCe,KCe);
  k_zreduce<<<2048,256,0,stream>>>(part,bip,bin,z,KCe);
  k_cc<<<4,256,0,stream>>>(cb,cc);
  k_qscan<<<dim3(32,16),256,0,stream>>>(z,cb,cc,bests,bestj);
  k_qfin<<<32,256,0,stream>>>(z,cb,bests,bestj,zqA,sse);
  k_gemm_mfma<16384,4096><<<dim3(128,KCd,2),256,0,stream>>>(zqA,Wop,Won,part,4096/KCd,KCd);
  k_hreduce<<<8192,256,0,stream>>>(part,bop,bon,hh,KCd);
  k_conv_out<<<dim3(64,4),256,0,stream>>>(hh,w2,b2,out);
  k_loss<<<1,256,0,stream>>>(sse,out);
}